// Round 2
// baseline (783.159 us; speedup 1.0000x reference)
//
#include <hip/hip_runtime.h>
#include <math.h>

// Problem constants (fixed by reference setup_inputs)
constexpr int B = 2, C = 16, H = 160, W = 192, S = 3, D = 48;
constexpr int HW = H * W;
constexpr int ND = 4;          // depth hypotheses per thread
constexpr int G = D / ND;      // depth groups

// ------------------------------------------------------------------
// Setup kernel: per (s,b) fold the full projection chain into
//   A = Ks * R * inv(Kref)  (3x3, f64)   q = Ks * t  (3, f64)
// so the main kernel does p = depth*(A*[u,v,1]) + q.
// ws layout: (s*B+b)*12 doubles = [A row-major 0..8][q 9..11]
// ------------------------------------------------------------------
__global__ void precompute_mats(const float* __restrict__ ref_intr,
                                const float* __restrict__ src_intr,
                                const float* __restrict__ ref_to_src,
                                double* __restrict__ ws)
{
    const int i = threadIdx.x;
    if (i >= S * B) return;
    const int b = i % B;

    // f64 adjugate inverse of ref intrinsics
    const float* Kp = ref_intr + b * 9;
    const double a00 = Kp[0], a01 = Kp[1], a02 = Kp[2];
    const double a10 = Kp[3], a11 = Kp[4], a12 = Kp[5];
    const double a20 = Kp[6], a21 = Kp[7], a22 = Kp[8];
    const double c00 =  (a11 * a22 - a12 * a21);
    const double c01 = -(a10 * a22 - a12 * a20);
    const double c02 =  (a10 * a21 - a11 * a20);
    const double c10 = -(a01 * a22 - a02 * a21);
    const double c11 =  (a00 * a22 - a02 * a20);
    const double c12 = -(a00 * a21 - a01 * a20);
    const double c20 =  (a01 * a12 - a02 * a11);
    const double c21 = -(a00 * a12 - a02 * a10);
    const double c22 =  (a00 * a11 - a01 * a10);
    const double invdet = 1.0 / (a00 * c00 + a01 * c01 + a02 * c02);
    const double iK[9] = { c00 * invdet, c10 * invdet, c20 * invdet,
                           c01 * invdet, c11 * invdet, c21 * invdet,
                           c02 * invdet, c12 * invdet, c22 * invdet };

    const float* Tp = ref_to_src + i * 16;  // 4x4 row-major
    const float* Ks = src_intr + i * 9;

    double M[9];  // R * inv(K)
    #pragma unroll
    for (int r = 0; r < 3; ++r)
        #pragma unroll
        for (int c = 0; c < 3; ++c)
            M[r * 3 + c] = (double)Tp[r * 4 + 0] * iK[0 + c]
                         + (double)Tp[r * 4 + 1] * iK[3 + c]
                         + (double)Tp[r * 4 + 2] * iK[6 + c];

    double* o = ws + i * 12;
    #pragma unroll
    for (int r = 0; r < 3; ++r) {
        #pragma unroll
        for (int c = 0; c < 3; ++c)
            o[r * 3 + c] = (double)Ks[r * 3 + 0] * M[0 + c]
                         + (double)Ks[r * 3 + 1] * M[3 + c]
                         + (double)Ks[r * 3 + 2] * M[6 + c];
        o[9 + r] = (double)Ks[r * 3 + 0] * (double)Tp[3]
                 + (double)Ks[r * 3 + 1] * (double)Tp[7]
                 + (double)Ks[r * 3 + 2] * (double)Tp[11];
    }
}

// ------------------------------------------------------------------
// Main kernel: one thread = one pixel x ND depths.
// Round-1 post-mortem: VALU/output dropped 33% but VGPR=176 capped
// occupancy at 2 waves/SIMD -> latency-bound (VALUBusy 26%).
// Fix: source-OUTER loop (only one ray live at a time), depths inner
// as static lambda expansion into named scalars, and
// __launch_bounds__(256,4) to force VGPR<=128 (4 waves/SIMD — the
// tier Round 0 ran 82% VALUBusy at). Numerics identical to Round 1.
// ------------------------------------------------------------------
__global__ __launch_bounds__(256, 4) void plane_sweep_kernel(
    const float* __restrict__ ref_feats,   // [B,C,H,W]
    const float* __restrict__ src_feats,   // [S,B,C,H,W]
    const float* __restrict__ depths,      // [D]
    const double* __restrict__ ws,         // [S*B][12]
    float* __restrict__ out)               // [B,D,H,W]
{
    const int idx = blockIdx.x * blockDim.x + threadIdx.x;
    const int total = B * G * HW;
    if (idx >= total) return;

    const int w  = idx % W;
    const int h  = (idx / W) % H;
    const int dg = (idx / HW) % G;   // wave-uniform (W % 64 == 0)
    const int b  = idx / (HW * G);   // wave-uniform

    // ---- ref fragment: load, zero-mean, norm (f32, well-conditioned) ----
    float f1[C];
    const float* rp = ref_feats + (b * C) * HW + h * W + w;
    float sum1 = 0.0f;
    #pragma unroll
    for (int c = 0; c < C; ++c) { f1[c] = rp[c * HW]; sum1 += f1[c]; }
    const float m1 = sum1 * (1.0f / C);
    float sq1 = 0.0f;
    #pragma unroll
    for (int c = 0; c < C; ++c) { f1[c] -= m1; sq1 = fmaf(f1[c], f1[c], sq1); }
    const float n1 = sqrtf(sq1);

    const double u = (double)w, v = (double)h;

    // depth values (wave-uniform), held as named f32 scalars
    const float dep0 = depths[dg * ND + 0];
    const float dep1 = depths[dg * ND + 1];
    const float dep2 = depths[dg * ND + 2];
    const float dep3 = depths[dg * ND + 3];

    // named accumulators (no runtime-indexed register arrays)
    float cost0 = 0.0f, cost1 = 0.0f, cost2 = 0.0f, cost3 = 0.0f;

    #pragma unroll 1   // runtime s is fine: nothing register-indexed by s;
                       // keeps only ONE source's ray/q live at a time.
    for (int s = 0; s < S; ++s) {
        const double* Aq = ws + (s * B + b) * 12;
        const double rx = Aq[0] * u + Aq[1] * v + Aq[2];
        const double ry = Aq[3] * u + Aq[4] * v + Aq[5];
        const double rz = Aq[6] * u + Aq[7] * v + Aq[8];
        const double q0 = Aq[9], q1 = Aq[10], q2 = Aq[11];

        const float* base = src_feats + ((size_t)(s * B + b) * C) * HW;

        auto sample = [&](double depth, float& cost) {
            const double p0 = fma(depth, rx, q0);
            const double p1 = fma(depth, ry, q1);
            const double p2 = fma(depth, rz, q2);

            const bool valid = p2 > 0.001;
            const double zs = fmax(p2, 0.001);
            // f64 reciprocal: v_rcp_f64 approx + 2 Newton steps (~1e-16 rel),
            // far cheaper than the IEEE f64 div chain.
#if __has_builtin(__builtin_amdgcn_rcp)
            double r = __builtin_amdgcn_rcp(zs);
#else
            double r = (double)__builtin_amdgcn_rcpf((float)zs);
#endif
            r = r * fma(-zs, r, 2.0);
            r = r * fma(-zs, r, 2.0);
            const double x = p0 * r;
            const double y = p1 * r;

            const double x0f = floor(x);
            const double y0f = floor(y);
            const double fx = x - x0f;
            const double fy = y - y0f;
            const int x0 = (int)x0f;
            const int y0 = (int)y0f;
            const int x1 = x0 + 1;
            const int y1 = y0 + 1;

            // weights in f64, rounded to f32 (validated numerics)
            const double gx = 1.0 - fx, gy = 1.0 - fy;
            const bool okx0 = (x0 >= 0) & (x0 < W);
            const bool okx1 = (x1 >= 0) & (x1 < W);
            const bool oky0 = (y0 >= 0) & (y0 < H);
            const bool oky1 = (y1 >= 0) & (y1 < H);
            const float w00 = (float)((valid & okx0 & oky0) ? gx * gy : 0.0);
            const float w01 = (float)((valid & okx1 & oky0) ? fx * gy : 0.0);
            const float w10 = (float)((valid & okx0 & oky1) ? gx * fy : 0.0);
            const float w11 = (float)((valid & okx1 & oky1) ? fx * fy : 0.0);

            const int x0c = min(max(x0, 0), W - 1);
            const int x1c = min(max(x1, 0), W - 1);
            const int y0c = min(max(y0, 0), H - 1);
            const int y1c = min(max(y1, 0), H - 1);
            const int off00 = y0c * W + x0c;
            const int off01 = y0c * W + x1c;
            const int off10 = y1c * W + x0c;
            const int off11 = y1c * W + x1c;

            // pass 1: bilinear + sum (f32)
            float f2[C];
            float sum2 = 0.0f;
            #pragma unroll
            for (int c = 0; c < C; ++c) {
                const float* p = base + c * HW;
                const float v00 = p[off00];
                const float v01 = p[off01];
                const float v10 = p[off10];
                const float v11 = p[off11];
                const float val = w00 * v00 + w01 * v01 + w10 * v10 + w11 * v11;
                f2[c] = val;
                sum2 += val;
            }
            // pass 2: mean-subtracted NCC reduction (f32).
            // Two-pass kept deliberately: single-pass sq2 = E[x^2]-E[x]^2
            // cancels catastrophically at ill-conditioned (n2 ~ 7e-4) pixels.
            const float m2 = sum2 * (1.0f / C);
            float sq2 = 0.0f;
            float dot = 0.0f;
            #pragma unroll
            for (int c = 0; c < C; ++c) {
                const float f2c = f2[c] - m2;
                sq2 = fmaf(f2c, f2c, sq2);
                dot = fmaf(f1[c], f2c, dot);
            }
            const float den = n1 * sqrtf(sq2) + 1e-6f;
            cost += dot / den;
        };

        sample((double)dep0, cost0);
        sample((double)dep1, cost1);
        sample((double)dep2, cost2);
        sample((double)dep3, cost3);
    }

    float* op = out + (size_t)((b * D + dg * ND) * HW + h * W + w);
    op[0 * HW] = cost0 * (1.0f / S);
    op[1 * HW] = cost1 * (1.0f / S);
    op[2 * HW] = cost2 * (1.0f / S);
    op[3 * HW] = cost3 * (1.0f / S);
}

extern "C" void kernel_launch(void* const* d_in, const int* in_sizes, int n_in,
                              void* d_out, int out_size, void* d_ws, size_t ws_size,
                              hipStream_t stream) {
    const float* ref_feats  = (const float*)d_in[0];
    const float* src_feats  = (const float*)d_in[1];
    const float* ref_intr   = (const float*)d_in[2];
    const float* src_intr   = (const float*)d_in[3];
    const float* ref_to_src = (const float*)d_in[4];
    const float* depths     = (const float*)d_in[5];
    float* out = (float*)d_out;
    double* ws = (double*)d_ws;   // needs S*B*12*8 = 576 bytes

    precompute_mats<<<1, 64, 0, stream>>>(ref_intr, src_intr, ref_to_src, ws);

    const int total = B * G * HW;
    const int block = 256;
    const int grid = (total + block - 1) / block;
    plane_sweep_kernel<<<grid, block, 0, stream>>>(
        ref_feats, src_feats, depths, ws, out);
}

// Round 3
// 233.805 us; speedup vs baseline: 3.3496x; 3.3496x over previous
//
#include <hip/hip_runtime.h>
#include <math.h>

// Problem constants (fixed by reference setup_inputs)
constexpr int B = 2, C = 16, H = 160, W = 192, S = 3, D = 48;
constexpr int HW = H * W;
constexpr int SB = S * B;

// Workspace layout (bytes):
//   [0,576)                 : per-(s,b) folded mats, f64 [SB][12]
//   [1024, 1024+NSRC_BYTES) : NHWC src feats  [SB][HW][C] f32
//   [NREF_OFF, +NREF_BYTES) : NHWC ref feats  [B][HW][C]  f32
constexpr size_t NSRC_OFF   = 1024;
constexpr size_t NSRC_BYTES = (size_t)SB * HW * C * 4;
constexpr size_t NREF_OFF   = NSRC_OFF + NSRC_BYTES;
constexpr size_t NREF_BYTES = (size_t)B * HW * C * 4;
constexpr size_t WS_NEEDED  = NREF_OFF + NREF_BYTES;   // ~15.73 MB

// ------------------------------------------------------------------
// Setup kernel: per (s,b) fold projection chain into
//   A = Ks * R * inv(Kref) (3x3 f64), q = Ks * t (f64)
// so main kernel does p = depth*(A*[u,v,1]) + q.
// ------------------------------------------------------------------
__global__ void precompute_mats(const float* __restrict__ ref_intr,
                                const float* __restrict__ src_intr,
                                const float* __restrict__ ref_to_src,
                                double* __restrict__ ws)
{
    const int i = threadIdx.x;
    if (i >= SB) return;
    const int b = i % B;

    const float* Kp = ref_intr + b * 9;
    const double a00 = Kp[0], a01 = Kp[1], a02 = Kp[2];
    const double a10 = Kp[3], a11 = Kp[4], a12 = Kp[5];
    const double a20 = Kp[6], a21 = Kp[7], a22 = Kp[8];
    const double c00 =  (a11 * a22 - a12 * a21);
    const double c01 = -(a10 * a22 - a12 * a20);
    const double c02 =  (a10 * a21 - a11 * a20);
    const double c10 = -(a01 * a22 - a02 * a21);
    const double c11 =  (a00 * a22 - a02 * a20);
    const double c12 = -(a00 * a21 - a01 * a20);
    const double c20 =  (a01 * a12 - a02 * a11);
    const double c21 = -(a00 * a12 - a02 * a10);
    const double c22 =  (a00 * a11 - a01 * a10);
    const double invdet = 1.0 / (a00 * c00 + a01 * c01 + a02 * c02);
    const double iK[9] = { c00 * invdet, c10 * invdet, c20 * invdet,
                           c01 * invdet, c11 * invdet, c21 * invdet,
                           c02 * invdet, c12 * invdet, c22 * invdet };

    const float* Tp = ref_to_src + i * 16;
    const float* Ks = src_intr + i * 9;

    double M[9];  // R * inv(K)
    #pragma unroll
    for (int r = 0; r < 3; ++r)
        #pragma unroll
        for (int c = 0; c < 3; ++c)
            M[r * 3 + c] = (double)Tp[r * 4 + 0] * iK[0 + c]
                         + (double)Tp[r * 4 + 1] * iK[3 + c]
                         + (double)Tp[r * 4 + 2] * iK[6 + c];

    double* o = ws + i * 12;
    #pragma unroll
    for (int r = 0; r < 3; ++r) {
        #pragma unroll
        for (int c = 0; c < 3; ++c)
            o[r * 3 + c] = (double)Ks[r * 3 + 0] * M[0 + c]
                         + (double)Ks[r * 3 + 1] * M[3 + c]
                         + (double)Ks[r * 3 + 2] * M[6 + c];
        o[9 + r] = (double)Ks[r * 3 + 0] * (double)Tp[3]
                 + (double)Ks[r * 3 + 1] * (double)Tp[7]
                 + (double)Ks[r * 3 + 2] * (double)Tp[11];
    }
}

// ------------------------------------------------------------------
// Transpose [*,C,H,W] -> [*,HW,C] so a bilinear tap = 64 contiguous
// bytes (4x dwordx4 with imm offsets) instead of 16 stride-HW scalars.
// Reads coalesced per c-plane; writes 4x float4 per thread, coalesced.
// ------------------------------------------------------------------
__global__ __launch_bounds__(256) void transpose_feats(
    const float* __restrict__ src_feats,   // [SB,C,HW]
    const float* __restrict__ ref_feats,   // [B,C,HW]
    float* __restrict__ nsrc,              // [SB,HW,C]
    float* __restrict__ nref)              // [B,HW,C]
{
    const int idx = blockIdx.x * blockDim.x + threadIdx.x;
    if (idx >= (SB + B) * HW) return;
    const int plane = idx / HW;
    const int hw = idx % HW;

    const float* in;
    float* outp;
    if (plane < SB) {
        in   = src_feats + (size_t)plane * C * HW + hw;
        outp = nsrc + ((size_t)plane * HW + hw) * C;
    } else {
        const int b = plane - SB;
        in   = ref_feats + (size_t)b * C * HW + hw;
        outp = nref + ((size_t)b * HW + hw) * C;
    }
    float t[C];
    #pragma unroll
    for (int c = 0; c < C; ++c) t[c] = in[(size_t)c * HW];
    #pragma unroll
    for (int k = 0; k < 4; ++k)
        ((float4*)outp)[k] = make_float4(t[4*k], t[4*k+1], t[4*k+2], t[4*k+3]);
}

// ------------------------------------------------------------------
// Main kernel. One thread = one (b,d,h,w) output (Round-0 grid: 45
// waves/SIMD of TLP, natural VGPR pressure — NO forced launch bounds;
// Round-2 showed the min-waves knob causes catastrophic spills).
// Geometry stays f64 (validated); NHWC path vector-gathers taps.
// ------------------------------------------------------------------
template<bool NHWC>
__global__ __launch_bounds__(256) void plane_sweep_kernel(
    const float* __restrict__ ref_feats,   // [B,C,H,W]
    const float* __restrict__ src_feats,   // [S,B,C,H,W]
    const float* __restrict__ nref,        // [B,HW,C]   (NHWC only)
    const float* __restrict__ nsrc,        // [SB,HW,C]  (NHWC only)
    const float* __restrict__ depths,      // [D]
    const double* __restrict__ mats,       // [SB][12]
    float* __restrict__ out)               // [B,D,H,W]
{
    const int idx = blockIdx.x * blockDim.x + threadIdx.x;
    const int total = B * D * HW;
    if (idx >= total) return;

    const int w = idx % W;
    const int h = (idx / W) % H;
    const int d = (idx / HW) % D;   // wave-uniform (W % 64 == 0)
    const int b = idx / (HW * D);   // wave-uniform

    // ---- ref fragment: load, zero-mean, norm (f32, well-conditioned) ----
    float f1[C];
    float sum1 = 0.0f;
    if (NHWC) {
        const float4* rp = (const float4*)(nref + ((size_t)b * HW + h * W + w) * C);
        #pragma unroll
        for (int k = 0; k < 4; ++k) {
            const float4 t = rp[k];
            f1[4*k+0] = t.x; f1[4*k+1] = t.y; f1[4*k+2] = t.z; f1[4*k+3] = t.w;
        }
    } else {
        const float* rp = ref_feats + (size_t)(b * C) * HW + h * W + w;
        #pragma unroll
        for (int c = 0; c < C; ++c) f1[c] = rp[(size_t)c * HW];
    }
    #pragma unroll
    for (int c = 0; c < C; ++c) sum1 += f1[c];
    const float m1 = sum1 * (1.0f / C);
    float sq1 = 0.0f;
    #pragma unroll
    for (int c = 0; c < C; ++c) { f1[c] -= m1; sq1 = fmaf(f1[c], f1[c], sq1); }
    const float n1 = sqrtf(sq1);

    const double u = (double)w, v = (double)h;
    const double depth = (double)depths[d];   // uniform -> scalar load
    float cost = 0.0f;

    #pragma unroll 1   // one source's f64 state live at a time
    for (int s = 0; s < S; ++s) {
        const double* Aq = mats + (s * B + b) * 12;
        const double rx = Aq[0] * u + Aq[1] * v + Aq[2];
        const double ry = Aq[3] * u + Aq[4] * v + Aq[5];
        const double rz = Aq[6] * u + Aq[7] * v + Aq[8];

        const double p0 = fma(depth, rx, Aq[9]);
        const double p1 = fma(depth, ry, Aq[10]);
        const double p2 = fma(depth, rz, Aq[11]);

        const bool valid = p2 > 0.001;
        const double zs = fmax(p2, 0.001);
        // f64 reciprocal: v_rcp_f64 approx + 2 Newton steps (~1e-16 rel)
#if __has_builtin(__builtin_amdgcn_rcp)
        double r = __builtin_amdgcn_rcp(zs);
#else
        double r = (double)__builtin_amdgcn_rcpf((float)zs);
#endif
        r = r * fma(-zs, r, 2.0);
        r = r * fma(-zs, r, 2.0);
        const double x = p0 * r;
        const double y = p1 * r;

        const double x0f = floor(x);
        const double y0f = floor(y);
        const double fx = x - x0f;
        const double fy = y - y0f;
        const int x0 = (int)x0f;
        const int y0 = (int)y0f;
        const int x1 = x0 + 1;
        const int y1 = y0 + 1;

        // weights in f64, rounded to f32 (validated numerics)
        const double gx = 1.0 - fx, gy = 1.0 - fy;
        const bool okx0 = (x0 >= 0) & (x0 < W);
        const bool okx1 = (x1 >= 0) & (x1 < W);
        const bool oky0 = (y0 >= 0) & (y0 < H);
        const bool oky1 = (y1 >= 0) & (y1 < H);
        const float w00 = (float)((valid & okx0 & oky0) ? gx * gy : 0.0);
        const float w01 = (float)((valid & okx1 & oky0) ? fx * gy : 0.0);
        const float w10 = (float)((valid & okx0 & oky1) ? gx * fy : 0.0);
        const float w11 = (float)((valid & okx1 & oky1) ? fx * fy : 0.0);

        const int x0c = min(max(x0, 0), W - 1);
        const int x1c = min(max(x1, 0), W - 1);
        const int y0c = min(max(y0, 0), H - 1);
        const int y1c = min(max(y1, 0), H - 1);
        const int off00 = y0c * W + x0c;
        const int off01 = y0c * W + x1c;
        const int off10 = y1c * W + x0c;
        const int off11 = y1c * W + x1c;

        // pass 1: bilinear + sum (f32)
        float f2[C];
        float sum2 = 0.0f;
        if (NHWC) {
            const float* bsrc = nsrc + (size_t)(s * B + b) * HW * C;
            const float4* p00 = (const float4*)(bsrc + (size_t)off00 * C);
            const float4* p01 = (const float4*)(bsrc + (size_t)off01 * C);
            const float4* p10 = (const float4*)(bsrc + (size_t)off10 * C);
            const float4* p11 = (const float4*)(bsrc + (size_t)off11 * C);
            #pragma unroll
            for (int k = 0; k < 4; ++k) {
                const float4 a = p00[k];
                const float4 bb = p01[k];
                const float4 cc = p10[k];
                const float4 dd = p11[k];
                const float v0 = w00 * a.x + w01 * bb.x + w10 * cc.x + w11 * dd.x;
                const float v1 = w00 * a.y + w01 * bb.y + w10 * cc.y + w11 * dd.y;
                const float v2 = w00 * a.z + w01 * bb.z + w10 * cc.z + w11 * dd.z;
                const float v3 = w00 * a.w + w01 * bb.w + w10 * cc.w + w11 * dd.w;
                f2[4*k+0] = v0; f2[4*k+1] = v1; f2[4*k+2] = v2; f2[4*k+3] = v3;
                sum2 += v0 + v1 + v2 + v3;
            }
        } else {
            const float* base = src_feats + ((size_t)(s * B + b) * C) * HW;
            #pragma unroll
            for (int c = 0; c < C; ++c) {
                const float* p = base + (size_t)c * HW;
                const float val = w00 * p[off00] + w01 * p[off01]
                                + w10 * p[off10] + w11 * p[off11];
                f2[c] = val;
                sum2 += val;
            }
        }

        // pass 2: mean-subtracted NCC reduction (f32).
        // Two-pass kept deliberately: single-pass sq2 = E[x^2]-E[x]^2
        // cancels catastrophically at ill-conditioned (n2 ~ 7e-4) pixels.
        const float m2 = sum2 * (1.0f / C);
        float sq2 = 0.0f;
        float dot = 0.0f;
        #pragma unroll
        for (int c = 0; c < C; ++c) {
            const float f2c = f2[c] - m2;
            sq2 = fmaf(f2c, f2c, sq2);
            dot = fmaf(f1[c], f2c, dot);
        }
        const float den = n1 * sqrtf(sq2) + 1e-6f;
        cost += dot / den;
    }

    out[idx] = cost * (1.0f / S);
}

extern "C" void kernel_launch(void* const* d_in, const int* in_sizes, int n_in,
                              void* d_out, int out_size, void* d_ws, size_t ws_size,
                              hipStream_t stream) {
    const float* ref_feats  = (const float*)d_in[0];
    const float* src_feats  = (const float*)d_in[1];
    const float* ref_intr   = (const float*)d_in[2];
    const float* src_intr   = (const float*)d_in[3];
    const float* ref_to_src = (const float*)d_in[4];
    const float* depths     = (const float*)d_in[5];
    float* out = (float*)d_out;
    double* mats = (double*)d_ws;

    precompute_mats<<<1, 64, 0, stream>>>(ref_intr, src_intr, ref_to_src, mats);

    const int total = B * D * HW;
    const int block = 256;
    const int grid = (total + block - 1) / block;

    if (ws_size >= WS_NEEDED) {
        float* nsrc = (float*)((char*)d_ws + NSRC_OFF);
        float* nref = (float*)((char*)d_ws + NREF_OFF);
        const int titems = (SB + B) * HW;
        transpose_feats<<<(titems + block - 1) / block, block, 0, stream>>>(
            src_feats, ref_feats, nsrc, nref);
        plane_sweep_kernel<true><<<grid, block, 0, stream>>>(
            ref_feats, src_feats, nref, nsrc, depths, mats, out);
    } else {
        plane_sweep_kernel<false><<<grid, block, 0, stream>>>(
            ref_feats, src_feats, nullptr, nullptr, depths, mats, out);
    }
}

// Round 4
// 171.686 us; speedup vs baseline: 4.5616x; 1.3618x over previous
//
#include <hip/hip_runtime.h>
#include <math.h>

// Problem constants (fixed by reference setup_inputs)
constexpr int B = 2, C = 16, H = 160, W = 192, S = 3, D = 48;
constexpr int HW = H * W;          // 30720 = 120 * 256
constexpr int SB = S * B;

// ------------------------------------------------------------------
// Setup kernel: per (s,b) fold projection chain into
//   A = Ks * R * inv(Kref) (3x3 f64), q = Ks * t (f64)
// so main kernel does p = depth*(A*[u,v,1]) + q.
// ws layout: (s*B+b)*12 doubles = [A row-major 0..8][q 9..11]
// ------------------------------------------------------------------
__global__ void precompute_mats(const float* __restrict__ ref_intr,
                                const float* __restrict__ src_intr,
                                const float* __restrict__ ref_to_src,
                                double* __restrict__ ws)
{
    const int i = threadIdx.x;
    if (i >= SB) return;
    const int b = i % B;

    const float* Kp = ref_intr + b * 9;
    const double a00 = Kp[0], a01 = Kp[1], a02 = Kp[2];
    const double a10 = Kp[3], a11 = Kp[4], a12 = Kp[5];
    const double a20 = Kp[6], a21 = Kp[7], a22 = Kp[8];
    const double c00 =  (a11 * a22 - a12 * a21);
    const double c01 = -(a10 * a22 - a12 * a20);
    const double c02 =  (a10 * a21 - a11 * a20);
    const double c10 = -(a01 * a22 - a02 * a21);
    const double c11 =  (a00 * a22 - a02 * a20);
    const double c12 = -(a00 * a21 - a01 * a20);
    const double c20 =  (a01 * a12 - a02 * a11);
    const double c21 = -(a00 * a12 - a02 * a10);
    const double c22 =  (a00 * a11 - a01 * a10);
    const double invdet = 1.0 / (a00 * c00 + a01 * c01 + a02 * c02);
    const double iK[9] = { c00 * invdet, c10 * invdet, c20 * invdet,
                           c01 * invdet, c11 * invdet, c21 * invdet,
                           c02 * invdet, c12 * invdet, c22 * invdet };

    const float* Tp = ref_to_src + i * 16;
    const float* Ks = src_intr + i * 9;

    double M[9];  // R * inv(K)
    #pragma unroll
    for (int r = 0; r < 3; ++r)
        #pragma unroll
        for (int c = 0; c < 3; ++c)
            M[r * 3 + c] = (double)Tp[r * 4 + 0] * iK[0 + c]
                         + (double)Tp[r * 4 + 1] * iK[3 + c]
                         + (double)Tp[r * 4 + 2] * iK[6 + c];

    double* o = ws + i * 12;
    #pragma unroll
    for (int r = 0; r < 3; ++r) {
        #pragma unroll
        for (int c = 0; c < 3; ++c)
            o[r * 3 + c] = (double)Ks[r * 3 + 0] * M[0 + c]
                         + (double)Ks[r * 3 + 1] * M[3 + c]
                         + (double)Ks[r * 3 + 2] * M[6 + c];
        o[9 + r] = (double)Ks[r * 3 + 0] * (double)Tp[3]
                 + (double)Ks[r * 3 + 1] * (double)Tp[7]
                 + (double)Ks[r * 3 + 2] * (double)Tp[11];
    }
}

// ------------------------------------------------------------------
// Main kernel. 2D grid: blockIdx.x = pixel tile (256 px), blockIdx.y
// = b*D + d. b/d/s are now PROVABLY wave-uniform -> depth, mats, and
// all per-channel plane bases scalarize (SGPR + s_add, saddr-form
// loads). Memory pattern stays NCHW stride-1 coalesced (Round-3
// lesson: NHWC per-thread 64B gathers amplify L1 transactions 4x).
// Geometry stays f64 (validated); no min-occupancy bound (Round-2
// lesson: forced VGPR caps cause catastrophic scratch spills).
// ------------------------------------------------------------------
__global__ __launch_bounds__(256) void plane_sweep_kernel(
    const float* __restrict__ ref_feats,   // [B,C,H,W]
    const float* __restrict__ src_feats,   // [S,B,C,H,W]
    const float* __restrict__ depths,      // [D]
    const double* __restrict__ mats,       // [SB][12]
    float* __restrict__ out)               // [B,D,H,W]
{
    const int pix = blockIdx.x * 256 + threadIdx.x;   // HW = 120*256 exact
    const int by  = blockIdx.y;                       // b*D + d (scalar)
    const int d   = by % D;                           // scalar
    const int b   = by / D;                           // scalar

    const int w = pix % W;
    const int h = pix / W;

    // ---- ref fragment: load, zero-mean, norm (f32, well-conditioned) ----
    // rb is wave-uniform -> 16 saddr loads sharing one voffset (pix*4).
    const float* rb = ref_feats + (size_t)b * C * HW;
    float f1[C];
    float sum1 = 0.0f;
    #pragma unroll
    for (int c = 0; c < C; ++c) { f1[c] = rb[c * HW + pix]; sum1 += f1[c]; }
    const float m1 = sum1 * (1.0f / C);
    float sq1 = 0.0f;
    #pragma unroll
    for (int c = 0; c < C; ++c) { f1[c] -= m1; sq1 = fmaf(f1[c], f1[c], sq1); }
    const float n1 = sqrtf(sq1);

    const double u = (double)w, v = (double)h;
    const double depth = (double)depths[d];    // scalar load
    float cost = 0.0f;

    #pragma unroll 1   // one source's f64 state live at a time; s uniform
    for (int s = 0; s < S; ++s) {
        const double* Aq = mats + (s * B + b) * 12;   // scalar loads
        const double rx = fma(u, Aq[0], fma(v, Aq[1], Aq[2]));
        const double ry = fma(u, Aq[3], fma(v, Aq[4], Aq[5]));
        const double rz = fma(u, Aq[6], fma(v, Aq[7], Aq[8]));

        const double p0 = fma(depth, rx, Aq[9]);
        const double p1 = fma(depth, ry, Aq[10]);
        const double p2 = fma(depth, rz, Aq[11]);

        const bool valid = p2 > 0.001;
        const double zs = fmax(p2, 0.001);
        // f64 reciprocal: v_rcp_f64 approx + 2 Newton steps (~1e-16 rel)
#if __has_builtin(__builtin_amdgcn_rcp)
        double r = __builtin_amdgcn_rcp(zs);
#else
        double r = (double)__builtin_amdgcn_rcpf((float)zs);
#endif
        r = r * fma(-zs, r, 2.0);
        r = r * fma(-zs, r, 2.0);
        const double x = p0 * r;
        const double y = p1 * r;

        const double x0f = floor(x);
        const double y0f = floor(y);
        const double fx = x - x0f;
        const double fy = y - y0f;
        const int x0 = (int)x0f;
        const int y0 = (int)y0f;
        const int x1 = x0 + 1;
        const int y1 = y0 + 1;

        // weights in f64, rounded to f32 (validated numerics)
        const double gx = 1.0 - fx, gy = 1.0 - fy;
        const bool okx0 = (x0 >= 0) & (x0 < W);
        const bool okx1 = (x1 >= 0) & (x1 < W);
        const bool oky0 = (y0 >= 0) & (y0 < H);
        const bool oky1 = (y1 >= 0) & (y1 < H);
        const float w00 = (float)((valid & okx0 & oky0) ? gx * gy : 0.0);
        const float w01 = (float)((valid & okx1 & oky0) ? fx * gy : 0.0);
        const float w10 = (float)((valid & okx0 & oky1) ? gx * fy : 0.0);
        const float w11 = (float)((valid & okx1 & oky1) ? fx * fy : 0.0);

        const int x0c = min(max(x0, 0), W - 1);
        const int x1c = min(max(x1, 0), W - 1);
        const int y0c = min(max(y0, 0), H - 1);
        const int y1c = min(max(y1, 0), H - 1);
        const int off00 = y0c * W + x0c;
        const int off01 = y0c * W + x1c;
        const int off10 = y1c * W + x0c;
        const int off11 = y1c * W + x1c;

        // sb is wave-uniform -> 64 saddr loads sharing 4 voffsets.
        const float* sb = src_feats + (size_t)(s * B + b) * C * HW;

        // pass 1: bilinear + sum (f32), coalesced stride-1 dword loads
        float f2[C];
        float sum2 = 0.0f;
        #pragma unroll
        for (int c = 0; c < C; ++c) {
            const float v00 = sb[c * HW + off00];
            const float v01 = sb[c * HW + off01];
            const float v10 = sb[c * HW + off10];
            const float v11 = sb[c * HW + off11];
            const float val = w00 * v00 + w01 * v01 + w10 * v10 + w11 * v11;
            f2[c] = val;
            sum2 += val;
        }
        // pass 2: mean-subtracted NCC reduction (f32).
        // Two-pass kept deliberately: single-pass sq2 = E[x^2]-E[x]^2
        // cancels catastrophically at ill-conditioned (n2 ~ 7e-4) pixels.
        const float m2 = sum2 * (1.0f / C);
        float sq2 = 0.0f;
        float dot = 0.0f;
        #pragma unroll
        for (int c = 0; c < C; ++c) {
            const float f2c = f2[c] - m2;
            sq2 = fmaf(f2c, f2c, sq2);
            dot = fmaf(f1[c], f2c, dot);
        }
        const float den = n1 * sqrtf(sq2) + 1e-6f;
        cost += dot / den;
    }

    // out base is wave-uniform (by*HW) -> saddr store with voffset pix*4.
    out[(size_t)by * HW + pix] = cost * (1.0f / S);
}

extern "C" void kernel_launch(void* const* d_in, const int* in_sizes, int n_in,
                              void* d_out, int out_size, void* d_ws, size_t ws_size,
                              hipStream_t stream) {
    const float* ref_feats  = (const float*)d_in[0];
    const float* src_feats  = (const float*)d_in[1];
    const float* ref_intr   = (const float*)d_in[2];
    const float* src_intr   = (const float*)d_in[3];
    const float* ref_to_src = (const float*)d_in[4];
    const float* depths     = (const float*)d_in[5];
    float* out = (float*)d_out;
    double* mats = (double*)d_ws;   // needs SB*12*8 = 576 bytes

    precompute_mats<<<1, 64, 0, stream>>>(ref_intr, src_intr, ref_to_src, mats);

    dim3 grid(HW / 256, B * D);     // 120 x 96
    plane_sweep_kernel<<<grid, dim3(256), 0, stream>>>(
        ref_feats, src_feats, depths, mats, out);
}